// Round 5
// baseline (98.985 us; speedup 1.0000x reference)
//
#include <hip/hip_runtime.h>

// Problem constants
#define B 16
#define Z 64
#define U 8
#define P 128
#define X 64
#define H 128
#define BZU (B * Z * U)       // 8192
#define BLOCKS 1024
#define M_PER_BLOCK (BZU / BLOCKS)   // 8 matrices per block
#define M_PER_WAVE (M_PER_BLOCK / 4) // 2 matrices per wave

typedef float f32x4 __attribute__((ext_vector_type(4)));

__device__ __forceinline__ float elu1(float v) {
    return v > 0.0f ? v : (expf(v) - 1.0f);
}

// Single fused kernel.
//  0) PREFETCH: each wave issues the 16 nt float4 loads of its first 16KB
//     Linv chunk (+ its Q row) BEFORE the encoder, so HBM is busy during the
//     encoder's L2 weight storm (1024 blocks x 224KB redundant reads ~6.6us).
//  1) redundant per-block encoder -> phi in LDS.
//  2) wave-independent nt stream of 2 matrices/wave, pure-shuffle reduction.
__global__ __launch_bounds__(256) void fused_kernel(
    const float* __restrict__ x,
    const float* __restrict__ Linv,
    const float* __restrict__ Q,
    const float* __restrict__ W1, const float* __restrict__ b1,
    const float* __restrict__ W2, const float* __restrict__ b2,
    const float* __restrict__ W3, const float* __restrict__ b3,
    const float* __restrict__ W4, const float* __restrict__ b4,
    const float* __restrict__ logSigEps,
    float* __restrict__ out_mu,
    float* __restrict__ out_cov)
{
    __shared__ float xs[X];
    __shared__ float hs[H];
    __shared__ float ps[2][H];
    __shared__ float phis[P];

    const int blk  = blockIdx.x;
    const int t    = threadIdx.x;
    const int b    = blk >> 6;         // 1024 blocks / 16 batch rows
    const int j    = t & (H - 1);
    const int half = t >> 7;
    const int wave = t >> 6;
    const int lane = t & 63;
    const int j4   = (lane & 31) * 4;  // column group, constant per lane
    const int r0   = lane >> 5;        // row = r0 + 2k
    const int m0   = blk * M_PER_BLOCK + wave * M_PER_WAVE;

    // ---- 0) x load first (oldest vmem op), then prefetch ----
    float xv = 0.0f;
    if (t < X) xv = x[b * X + t];

    const f32x4* __restrict__ Lp0 =
        (const f32x4*)Linv + (size_t)m0 * (P * P / 4);
    f32x4 Lb0[16];
    #pragma unroll
    for (int k2 = 0; k2 < 16; ++k2)
        Lb0[k2] = __builtin_nontemporal_load(Lp0 + lane + 64 * k2);
    const float4 qv0 = *(const float4*)(Q + (size_t)m0 * P + j4);
    __builtin_amdgcn_sched_barrier(0);   // pin prefetch issue before encoder

    if (t < X) xs[t] = xv;               // waits vmcnt for x only (in-order)
    __syncthreads();

    // ---- 1) encoder (split-k over 2 halves, combined via LDS) ----
    { // layer 1: X=64 -> H
        float v = 0.0f; const int k0 = half * 32;
        #pragma unroll 8
        for (int k = k0; k < k0 + 32; ++k) v = fmaf(xs[k], W1[k * H + j], v);
        ps[half][j] = v;
    }
    __syncthreads();
    if (t < H) hs[j] = elu1(b1[j] + ps[0][j] + ps[1][j]);
    __syncthreads();

    { // layer 2
        float v = 0.0f; const int k0 = half * 64;
        #pragma unroll 8
        for (int k = k0; k < k0 + 64; ++k) v = fmaf(hs[k], W2[k * H + j], v);
        ps[half][j] = v;
    }
    __syncthreads();
    if (t < H) hs[j] = elu1(b2[j] + ps[0][j] + ps[1][j]);
    __syncthreads();

    { // layer 3
        float v = 0.0f; const int k0 = half * 64;
        #pragma unroll 8
        for (int k = k0; k < k0 + 64; ++k) v = fmaf(hs[k], W3[k * H + j], v);
        ps[half][j] = v;
    }
    __syncthreads();
    if (t < H) hs[j] = elu1(b3[j] + ps[0][j] + ps[1][j]);
    __syncthreads();

    { // layer 4: H -> P, no activation
        float v = 0.0f; const int k0 = half * 64;
        #pragma unroll 8
        for (int k = k0; k < k0 + 64; ++k) v = fmaf(hs[k], W4[k * P + j], v);
        ps[half][j] = v;
    }
    __syncthreads();
    if (t < H) phis[j] = b4[j] + ps[0][j] + ps[1][j];
    __syncthreads();

    // ---- 2) wave-independent bilinear stream ----
    const float pp0 = phis[j4 + 0], pp1 = phis[j4 + 1],
                pp2 = phis[j4 + 2], pp3 = phis[j4 + 3];

    // matrix m0: chunk 0 comes from the prefetch
    {
        float mu = 0.0f, sg = 0.0f;
        #pragma unroll
        for (int k2 = 0; k2 < 16; ++k2) {
            const f32x4 L = Lb0[k2];
            const float pi = phis[r0 + 2 * k2];
            const float dq = L[0] * qv0.x + L[1] * qv0.y + L[2] * qv0.z + L[3] * qv0.w;
            const float dp = L[0] * pp0 + L[1] * pp1 + L[2] * pp2 + L[3] * pp3;
            mu = fmaf(pi, dq, mu);
            sg = fmaf(pi, dp, sg);
        }
        #pragma unroll
        for (int c = 1; c < 4; ++c) {
            f32x4 Lb[16];
            #pragma unroll
            for (int k2 = 0; k2 < 16; ++k2)
                Lb[k2] = __builtin_nontemporal_load(Lp0 + lane + 64 * (16 * c + k2));
            float pi[16];
            #pragma unroll
            for (int k2 = 0; k2 < 16; ++k2) pi[k2] = phis[r0 + 32 * c + 2 * k2];
            #pragma unroll
            for (int k2 = 0; k2 < 16; ++k2) {
                const f32x4 L = Lb[k2];
                const float dq = L[0] * qv0.x + L[1] * qv0.y + L[2] * qv0.z + L[3] * qv0.w;
                const float dp = L[0] * pp0 + L[1] * pp1 + L[2] * pp2 + L[3] * pp3;
                mu = fmaf(pi[k2], dq, mu);
                sg = fmaf(pi[k2], dp, sg);
            }
        }
        #pragma unroll
        for (int off = 32; off > 0; off >>= 1) {
            mu += __shfl_down(mu, off, 64);
            sg += __shfl_down(sg, off, 64);
        }
        if (lane == 0) {
            out_mu[m0]  = mu;
            out_cov[m0] = expf(logSigEps[m0 & (U - 1)]) * (1.0f + sg);
        }
    }

    // matrix m0+1: all 4 chunks fresh
    {
        const int m = m0 + 1;
        const f32x4* __restrict__ Lp =
            (const f32x4*)Linv + (size_t)m * (P * P / 4);
        const float4 qv = *(const float4*)(Q + (size_t)m * P + j4);
        float mu = 0.0f, sg = 0.0f;
        #pragma unroll
        for (int c = 0; c < 4; ++c) {
            f32x4 Lb[16];
            #pragma unroll
            for (int k2 = 0; k2 < 16; ++k2)
                Lb[k2] = __builtin_nontemporal_load(Lp + lane + 64 * (16 * c + k2));
            float pi[16];
            #pragma unroll
            for (int k2 = 0; k2 < 16; ++k2) pi[k2] = phis[r0 + 32 * c + 2 * k2];
            #pragma unroll
            for (int k2 = 0; k2 < 16; ++k2) {
                const f32x4 L = Lb[k2];
                const float dq = L[0] * qv.x + L[1] * qv.y + L[2] * qv.z + L[3] * qv.w;
                const float dp = L[0] * pp0 + L[1] * pp1 + L[2] * pp2 + L[3] * pp3;
                mu = fmaf(pi[k2], dq, mu);
                sg = fmaf(pi[k2], dp, sg);
            }
        }
        #pragma unroll
        for (int off = 32; off > 0; off >>= 1) {
            mu += __shfl_down(mu, off, 64);
            sg += __shfl_down(sg, off, 64);
        }
        if (lane == 0) {
            out_mu[m]  = mu;
            out_cov[m] = expf(logSigEps[m & (U - 1)]) * (1.0f + sg);
        }
    }
}

extern "C" void kernel_launch(void* const* d_in, const int* in_sizes, int n_in,
                              void* d_out, int out_size, void* d_ws, size_t ws_size,
                              hipStream_t stream) {
    const float* x        = (const float*)d_in[0];
    const float* Linv     = (const float*)d_in[1];
    const float* Q        = (const float*)d_in[2];
    const float* W1       = (const float*)d_in[3];
    const float* b1       = (const float*)d_in[4];
    const float* W2       = (const float*)d_in[5];
    const float* b2       = (const float*)d_in[6];
    const float* W3       = (const float*)d_in[7];
    const float* b3       = (const float*)d_in[8];
    const float* W4       = (const float*)d_in[9];
    const float* b4       = (const float*)d_in[10];
    const float* logSigEps= (const float*)d_in[11];

    float* out_mu  = (float*)d_out;           // (B,Z,U,1) flat: 8192
    float* out_cov = (float*)d_out + BZU;     // (B,Z,U)   flat: 8192

    fused_kernel<<<BLOCKS, 256, 0, stream>>>(
        x, Linv, Q, W1, b1, W2, b2, W3, b3, W4, b4, logSigEps,
        out_mu, out_cov);
}

// Round 6
// 88.535 us; speedup vs baseline: 1.1180x; 1.1180x over previous
//
#include <hip/hip_runtime.h>

// Problem constants
#define B 16
#define Z 64
#define U 8
#define P 128
#define X 64
#define H 128
#define BZU (B * Z * U)       // 8192
#define BLOCKS 256
#define THREADS 1024
#define M_PER_BLOCK (BZU / BLOCKS)     // 32 matrices per block
#define M_PER_WAVE 2                   // 16 waves * 2 = 32

typedef float f32x4 __attribute__((ext_vector_type(4)));

__device__ __forceinline__ float elu1(float v) {
    return v > 0.0f ? v : (expf(v) - 1.0f);
}

// Single fused kernel, 256 blocks x 1024 threads (one 16-wave block per CU).
// Rationale: the redundant per-block encoder's L2 weight storm scales with
// block count (224KB/block). 1024 blocks -> 229MB (~6.6us HBM-idle);
// 256 blocks -> 57MB (~1.7us). Same stream TLP (16 waves/CU).
__global__ __launch_bounds__(THREADS, 4) void fused_kernel(
    const float* __restrict__ x,
    const float* __restrict__ Linv,
    const float* __restrict__ Q,
    const float* __restrict__ W1, const float* __restrict__ b1,
    const float* __restrict__ W2, const float* __restrict__ b2,
    const float* __restrict__ W3, const float* __restrict__ b3,
    const float* __restrict__ W4, const float* __restrict__ b4,
    const float* __restrict__ logSigEps,
    float* __restrict__ out_mu,
    float* __restrict__ out_cov)
{
    __shared__ float xs[X];
    __shared__ float hs[H];
    __shared__ float ps[8][H];
    __shared__ float phis[P];

    const int blk  = blockIdx.x;
    const int t    = threadIdx.x;
    const int b    = blk >> 4;         // 256 blocks / 16 batch rows
    const int j    = t & (H - 1);      // output neuron
    const int sl   = t >> 7;           // split-k slice 0..7
    const int wave = t >> 6;
    const int lane = t & 63;
    const int j4   = (lane & 31) * 4;  // column group, constant per lane
    const int r0   = lane >> 5;        // row = r0 + 2k

    // ---- encoder (8-way split-k, combined via LDS) ----
    if (t < X) xs[t] = x[b * X + t];
    __syncthreads();

    { // layer 1: X=64 -> H; each slice sums 8 k's
        float v = 0.0f; const int k0 = sl * 8;
        #pragma unroll
        for (int k = k0; k < k0 + 8; ++k) v = fmaf(xs[k], W1[k * H + j], v);
        ps[sl][j] = v;
    }
    __syncthreads();
    if (t < H) {
        float v = b1[j];
        #pragma unroll
        for (int s = 0; s < 8; ++s) v += ps[s][j];
        hs[j] = elu1(v);
    }
    __syncthreads();

    { // layer 2: H -> H; each slice sums 16 k's
        float v = 0.0f; const int k0 = sl * 16;
        #pragma unroll
        for (int k = k0; k < k0 + 16; ++k) v = fmaf(hs[k], W2[k * H + j], v);
        ps[sl][j] = v;
    }
    __syncthreads();
    if (t < H) {
        float v = b2[j];
        #pragma unroll
        for (int s = 0; s < 8; ++s) v += ps[s][j];
        hs[j] = elu1(v);
    }
    __syncthreads();

    { // layer 3
        float v = 0.0f; const int k0 = sl * 16;
        #pragma unroll
        for (int k = k0; k < k0 + 16; ++k) v = fmaf(hs[k], W3[k * H + j], v);
        ps[sl][j] = v;
    }
    __syncthreads();
    if (t < H) {
        float v = b3[j];
        #pragma unroll
        for (int s = 0; s < 8; ++s) v += ps[s][j];
        hs[j] = elu1(v);
    }
    __syncthreads();

    { // layer 4: H -> P, no activation
        float v = 0.0f; const int k0 = sl * 16;
        #pragma unroll
        for (int k = k0; k < k0 + 16; ++k) v = fmaf(hs[k], W4[k * P + j], v);
        ps[sl][j] = v;
    }
    __syncthreads();
    if (t < H) {
        float v = b4[j];
        #pragma unroll
        for (int s = 0; s < 8; ++s) v += ps[s][j];
        phis[j] = v;
    }
    __syncthreads();

    // ---- wave-independent bilinear stream (2 matrices per wave) ----
    const float pp0 = phis[j4 + 0], pp1 = phis[j4 + 1],
                pp2 = phis[j4 + 2], pp3 = phis[j4 + 3];

    #pragma unroll
    for (int i = 0; i < M_PER_WAVE; ++i) {
        const int m = blk * M_PER_BLOCK + wave * M_PER_WAVE + i;
        const float4 qv = *(const float4*)(Q + (size_t)m * P + j4);
        const f32x4* __restrict__ Lp =
            (const f32x4*)Linv + (size_t)m * (P * P / 4);

        float mu = 0.0f, sg = 0.0f;
        #pragma unroll
        for (int c = 0; c < 4; ++c) {
            f32x4 Lb[16];
            #pragma unroll
            for (int k2 = 0; k2 < 16; ++k2)
                Lb[k2] = __builtin_nontemporal_load(Lp + lane + 64 * (16 * c + k2));
            float pi[16];
            #pragma unroll
            for (int k2 = 0; k2 < 16; ++k2) pi[k2] = phis[r0 + 32 * c + 2 * k2];
            #pragma unroll
            for (int k2 = 0; k2 < 16; ++k2) {
                const f32x4 L = Lb[k2];
                const float dq = L[0] * qv.x + L[1] * qv.y + L[2] * qv.z + L[3] * qv.w;
                const float dp = L[0] * pp0 + L[1] * pp1 + L[2] * pp2 + L[3] * pp3;
                mu = fmaf(pi[k2], dq, mu);
                sg = fmaf(pi[k2], dp, sg);
            }
        }

        #pragma unroll
        for (int off = 32; off > 0; off >>= 1) {
            mu += __shfl_down(mu, off, 64);
            sg += __shfl_down(sg, off, 64);
        }
        if (lane == 0) {
            out_mu[m]  = mu;
            out_cov[m] = expf(logSigEps[m & (U - 1)]) * (1.0f + sg);
        }
    }
}

extern "C" void kernel_launch(void* const* d_in, const int* in_sizes, int n_in,
                              void* d_out, int out_size, void* d_ws, size_t ws_size,
                              hipStream_t stream) {
    const float* x        = (const float*)d_in[0];
    const float* Linv     = (const float*)d_in[1];
    const float* Q        = (const float*)d_in[2];
    const float* W1       = (const float*)d_in[3];
    const float* b1       = (const float*)d_in[4];
    const float* W2       = (const float*)d_in[5];
    const float* b2       = (const float*)d_in[6];
    const float* W3       = (const float*)d_in[7];
    const float* b3       = (const float*)d_in[8];
    const float* W4       = (const float*)d_in[9];
    const float* b4       = (const float*)d_in[10];
    const float* logSigEps= (const float*)d_in[11];

    float* out_mu  = (float*)d_out;           // (B,Z,U,1) flat: 8192
    float* out_cov = (float*)d_out + BZU;     // (B,Z,U)   flat: 8192

    fused_kernel<<<BLOCKS, THREADS, 0, stream>>>(
        x, Linv, Q, W1, b1, W2, b2, W3, b3, W4, b4, logSigEps,
        out_mu, out_cov);
}

// Round 7
// 88.305 us; speedup vs baseline: 1.1209x; 1.0026x over previous
//
#include <hip/hip_runtime.h>

// Problem constants
#define B 16
#define Z 64
#define U 8
#define P 128
#define X 64
#define H 128
#define BZU (B * Z * U)       // 8192
#define BLOCKS 256
#define THREADS 1024
#define M_PER_BLOCK (BZU / BLOCKS)     // 32 matrices per block
#define M_PER_WAVE 2                   // 16 waves * 2 = 32

typedef float f32x4 __attribute__((ext_vector_type(4)));

__device__ __forceinline__ float elu1(float v) {
    return v > 0.0f ? v : (expf(v) - 1.0f);
}

// 256 blocks x 1024 threads (one 16-wave block per CU).
// Encoder: all weight slices prefetched into registers at kernel start so the
// four per-layer global-latency waits collapse into one. Stream: two 8-deep
// register buffers software-pipeline the 16 load-groups (2 matrices) so >=8
// nt loads are always in flight (no WAR gap between chunks, reduce of matrix
// 0 overlaps loads of matrix 1).
__global__ __launch_bounds__(THREADS, 4) void fused_kernel(
    const float* __restrict__ x,
    const float* __restrict__ Linv,
    const float* __restrict__ Q,
    const float* __restrict__ W1, const float* __restrict__ b1,
    const float* __restrict__ W2, const float* __restrict__ b2,
    const float* __restrict__ W3, const float* __restrict__ b3,
    const float* __restrict__ W4, const float* __restrict__ b4,
    const float* __restrict__ logSigEps,
    float* __restrict__ out_mu,
    float* __restrict__ out_cov)
{
    __shared__ float xs[X];
    __shared__ float hs[H];
    __shared__ float ps[8][H];
    __shared__ float phis[P];

    const int blk  = blockIdx.x;
    const int t    = threadIdx.x;
    const int b    = blk >> 4;         // 256 blocks / 16 batch rows
    const int j    = t & (H - 1);      // output neuron
    const int sl   = t >> 7;           // split-k slice 0..7
    const int wave = t >> 6;
    const int lane = t & 63;
    const int j4   = (lane & 31) * 4;  // column group, constant per lane
    const int r0   = lane >> 5;        // row = r0 + 2k
    const int m0   = blk * M_PER_BLOCK + wave * M_PER_WAVE;

    // ---- prefetch x + ALL weight slices into registers (one latency wait) ----
    float xv = 0.0f;
    if (t < X) xv = x[b * X + t];

    const int k1 = sl * 8;             // layer-1 k-range (X=64 split 8 ways)
    const int k0 = sl * 16;            // layers 2-4 k-range (H=128 split 8 ways)
    float w1r[8], w2r[16], w3r[16], w4r[16];
    #pragma unroll
    for (int e = 0; e < 8; ++e)  w1r[e] = W1[(k1 + e) * H + j];
    #pragma unroll
    for (int e = 0; e < 16; ++e) w2r[e] = W2[(k0 + e) * H + j];
    #pragma unroll
    for (int e = 0; e < 16; ++e) w3r[e] = W3[(k0 + e) * H + j];
    #pragma unroll
    for (int e = 0; e < 16; ++e) w4r[e] = W4[(k0 + e) * P + j];

    if (t < X) xs[t] = xv;
    __syncthreads();

    // ---- encoder (8-way split-k, partials combined via LDS) ----
    { // layer 1
        float v = 0.0f;
        #pragma unroll
        for (int e = 0; e < 8; ++e) v = fmaf(xs[k1 + e], w1r[e], v);
        ps[sl][j] = v;
    }
    __syncthreads();
    if (t < H) {
        float v = b1[j];
        #pragma unroll
        for (int s = 0; s < 8; ++s) v += ps[s][j];
        hs[j] = elu1(v);
    }
    __syncthreads();

    { // layer 2
        float v = 0.0f;
        #pragma unroll
        for (int e = 0; e < 16; ++e) v = fmaf(hs[k0 + e], w2r[e], v);
        ps[sl][j] = v;
    }
    __syncthreads();
    if (t < H) {
        float v = b2[j];
        #pragma unroll
        for (int s = 0; s < 8; ++s) v += ps[s][j];
        hs[j] = elu1(v);
    }
    __syncthreads();

    { // layer 3
        float v = 0.0f;
        #pragma unroll
        for (int e = 0; e < 16; ++e) v = fmaf(hs[k0 + e], w3r[e], v);
        ps[sl][j] = v;
    }
    __syncthreads();
    if (t < H) {
        float v = b3[j];
        #pragma unroll
        for (int s = 0; s < 8; ++s) v += ps[s][j];
        hs[j] = elu1(v);
    }
    __syncthreads();

    { // layer 4 (no activation)
        float v = 0.0f;
        #pragma unroll
        for (int e = 0; e < 16; ++e) v = fmaf(hs[k0 + e], w4r[e], v);
        ps[sl][j] = v;
    }
    __syncthreads();
    if (t < H) {
        float v = b4[j];
        #pragma unroll
        for (int s = 0; s < 8; ++s) v += ps[s][j];
        phis[j] = v;
    }
    __syncthreads();

    // ---- software-pipelined bilinear stream (2 matrices per wave) ----
    const float pp0 = phis[j4 + 0], pp1 = phis[j4 + 1],
                pp2 = phis[j4 + 2], pp3 = phis[j4 + 3];

    const f32x4* __restrict__ Lp0 =
        (const f32x4*)Linv + (size_t)m0 * (P * P / 4);
    const f32x4* __restrict__ Lp1 = Lp0 + (P * P / 4);
    const float4 qv0 = *(const float4*)(Q + (size_t)m0 * P + j4);
    const float4 qv1 = *(const float4*)(Q + (size_t)(m0 + 1) * P + j4);

    f32x4 bufA[8], bufB[8];

    // prologue: groups 0 and 1 in flight
    #pragma unroll
    for (int e = 0; e < 8; ++e)
        bufA[e] = __builtin_nontemporal_load(Lp0 + lane + 64 * e);
    #pragma unroll
    for (int e = 0; e < 8; ++e)
        bufB[e] = __builtin_nontemporal_load(Lp0 + lane + 64 * (8 + e));

    float mu = 0.0f, sg = 0.0f;
    #pragma unroll
    for (int g = 0; g < 16; ++g) {
        f32x4* cur = (g & 1) ? bufB : bufA;
        const float qx = (g < 8) ? qv0.x : qv1.x;
        const float qy = (g < 8) ? qv0.y : qv1.y;
        const float qz = (g < 8) ? qv0.z : qv1.z;
        const float qw = (g < 8) ? qv0.w : qv1.w;
        const int gg = g & 7;

        #pragma unroll
        for (int e = 0; e < 8; ++e) {
            const f32x4 L = cur[e];
            const float pi = phis[r0 + 16 * gg + 2 * e];
            const float dq = L[0] * qx + L[1] * qy + L[2] * qz + L[3] * qw;
            const float dp = L[0] * pp0 + L[1] * pp1 + L[2] * pp2 + L[3] * pp3;
            mu = fmaf(pi, dq, mu);
            sg = fmaf(pi, dp, sg);
        }

        if (g < 14) {
            const int gn = g + 2;                       // next group into cur
            const f32x4* __restrict__ Lp = (gn < 8) ? Lp0 : Lp1;
            const int gh = gn & 7;
            #pragma unroll
            for (int e = 0; e < 8; ++e)
                cur[e] = __builtin_nontemporal_load(Lp + lane + 64 * (8 * gh + e));
        }

        if (g == 7) {   // matrix m0 complete: reduce + store, reset accumulators
            #pragma unroll
            for (int off = 32; off > 0; off >>= 1) {
                mu += __shfl_down(mu, off, 64);
                sg += __shfl_down(sg, off, 64);
            }
            if (lane == 0) {
                out_mu[m0]  = mu;
                out_cov[m0] = expf(logSigEps[m0 & (U - 1)]) * (1.0f + sg);
            }
            mu = 0.0f; sg = 0.0f;
        }
    }

    // matrix m0+1 reduce + store
    #pragma unroll
    for (int off = 32; off > 0; off >>= 1) {
        mu += __shfl_down(mu, off, 64);
        sg += __shfl_down(sg, off, 64);
    }
    if (lane == 0) {
        const int m = m0 + 1;
        out_mu[m]  = mu;
        out_cov[m] = expf(logSigEps[m & (U - 1)]) * (1.0f + sg);
    }
}

extern "C" void kernel_launch(void* const* d_in, const int* in_sizes, int n_in,
                              void* d_out, int out_size, void* d_ws, size_t ws_size,
                              hipStream_t stream) {
    const float* x        = (const float*)d_in[0];
    const float* Linv     = (const float*)d_in[1];
    const float* Q        = (const float*)d_in[2];
    const float* W1       = (const float*)d_in[3];
    const float* b1       = (const float*)d_in[4];
    const float* W2       = (const float*)d_in[5];
    const float* b2       = (const float*)d_in[6];
    const float* W3       = (const float*)d_in[7];
    const float* b3       = (const float*)d_in[8];
    const float* W4       = (const float*)d_in[9];
    const float* b4       = (const float*)d_in[10];
    const float* logSigEps= (const float*)d_in[11];

    float* out_mu  = (float*)d_out;           // (B,Z,U,1) flat: 8192
    float* out_cov = (float*)d_out + BZU;     // (B,Z,U)   flat: 8192

    fused_kernel<<<BLOCKS, THREADS, 0, stream>>>(
        x, Linv, Q, W1, b1, W2, b2, W3, b3, W4, b4, logSigEps,
        out_mu, out_cov);
}